// Round 6
// baseline (1151.344 us; speedup 1.0000x reference)
//
#include <hip/hip_runtime.h>

// Problem constants
#define D_  1024
#define S_  2048
#define B_  4
#define H_  16
#define HD_ 64
#define BS_ (B_*S_)   // 8192 rows

typedef __attribute__((ext_vector_type(8))) short short8;   // 8 bf16 = 4 VGPRs
typedef __attribute__((ext_vector_type(4))) float floatx4;  // MFMA C/D

// Workspace layout (byte offsets), 72 MB total.
#define WS_XB ((size_t)0)            // 16 MB bf16 x
#define WS_WQ ((size_t)16 << 20)     // 2 MB bf16 Wq
#define WS_WK ((size_t)18 << 20)
#define WS_WV ((size_t)20 << 20)
#define WS_WO ((size_t)22 << 20)
#define WS_Q  ((size_t)24 << 20)     // 16 MB bf16 Q [b,h,s,hd]
#define WS_KK ((size_t)40 << 20)     // 16 MB bf16 K [b,h,s,hd]
#define WS_VT ((size_t)56 << 20)     // 16 MB bf16 V^T [b,h,hd,s]
#define WS_Y  WS_Q                   // y (fp32, 32 MB) overlays Q+K after attn

static __device__ __forceinline__ unsigned short f2bf(float f) {
  unsigned u = __builtin_bit_cast(unsigned, f);
  unsigned r = (u + 0x7fffu + ((u >> 16) & 1u)) >> 16;  // RNE
  return (unsigned short)r;
}

// ---------------------------------------------------------------------------
// Kernel 0: fp32 -> bf16 convert (RNE), 4 elements per thread.
// ---------------------------------------------------------------------------
__global__ __launch_bounds__(256) void cvt_f32_bf16(
    const float* __restrict__ src, unsigned short* __restrict__ dst, int n4)
{
  int i = blockIdx.x * 256 + threadIdx.x;
  if (i < n4) {
    float4 v = ((const float4*)src)[i];
    ushort4 o;
    o.x = f2bf(v.x); o.y = f2bf(v.y); o.z = f2bf(v.z); o.w = f2bf(v.w);
    ((ushort4*)dst)[i] = o;
  }
}

// ---------------------------------------------------------------------------
// Kernel 1: QKV projection. C[m,n] = sum_k X[m,k]*W[n,k] + b[n]  (x @ W.T + b)
// mode (blockIdx.z): 0->Q [b,h,s,hd]; 1->K [b,h,s,hd]; 2->V^T [b,h,hd,s].
// A-frag: row=lane&15, k=quad*8+j. B-frag: col=lane&15, same k.
// C/D: col=lane&15, row=quad*4+reg  (HW-verified: round-4 probe chose swap=0).
// ---------------------------------------------------------------------------
__global__ __launch_bounds__(256) void proj_qkv(
    const unsigned short* __restrict__ X,
    const unsigned short* __restrict__ Wq, const float* __restrict__ bq,
    const unsigned short* __restrict__ Wk, const float* __restrict__ bk,
    const unsigned short* __restrict__ Wv, const float* __restrict__ bv,
    unsigned short* __restrict__ Qo, unsigned short* __restrict__ Ko,
    unsigned short* __restrict__ Vo)
{
  const int mode = blockIdx.z;
  const unsigned short* W = (mode == 0) ? Wq : ((mode == 1) ? Wk : Wv);
  const float* bias       = (mode == 0) ? bq : ((mode == 1) ? bk : bv);
  unsigned short* dst     = (mode == 0) ? Qo : ((mode == 1) ? Ko : Vo);

  const int wv   = threadIdx.x >> 6;
  const int lane = threadIdx.x & 63;
  const int c    = lane & 15;
  const int quad = lane >> 4;
  const int m0   = blockIdx.x * 64 + wv * 16;
  const int n0   = blockIdx.y * 64;

  const unsigned short* arow = X + (size_t)(m0 + c) * D_ + quad * 8;
  const unsigned short* brow = W + (size_t)(n0 + c) * D_ + quad * 8;

  floatx4 acc0 = {0.f,0.f,0.f,0.f}, acc1 = {0.f,0.f,0.f,0.f};
  floatx4 acc2 = {0.f,0.f,0.f,0.f}, acc3 = {0.f,0.f,0.f,0.f};

  for (int k0 = 0; k0 < D_; k0 += 32) {
    short8 a  = *(const short8*)(arow + k0);
    short8 b0 = *(const short8*)(brow + k0);
    short8 b1 = *(const short8*)(brow + 16 * D_ + k0);
    short8 b2 = *(const short8*)(brow + 32 * D_ + k0);
    short8 b3 = *(const short8*)(brow + 48 * D_ + k0);
    acc0 = __builtin_amdgcn_mfma_f32_16x16x32_bf16(a, b0, acc0, 0, 0, 0);
    acc1 = __builtin_amdgcn_mfma_f32_16x16x32_bf16(a, b1, acc1, 0, 0, 0);
    acc2 = __builtin_amdgcn_mfma_f32_16x16x32_bf16(a, b2, acc2, 0, 0, 0);
    acc3 = __builtin_amdgcn_mfma_f32_16x16x32_bf16(a, b3, acc3, 0, 0, 0);
  }

  const int b  = m0 >> 11;          // batch (2048 rows per batch)
  const int s0 = m0 & (S_ - 1);
  const int h  = n0 >> 6;           // head

  floatx4 accs[4] = {acc0, acc1, acc2, acc3};
  #pragma unroll
  for (int j = 0; j < 4; ++j) {
    const int n     = n0 + j * 16 + c;
    const float bv_ = bias[n];
    const int hd    = j * 16 + c;
    if (mode < 2) {
      size_t base = ((size_t)((b * H_ + h) * S_ + s0 + quad * 4)) * HD_ + hd;
      #pragma unroll
      for (int r = 0; r < 4; ++r)
        dst[base + (size_t)r * HD_] = f2bf(accs[j][r] + bv_);
    } else {
      size_t base = ((size_t)((b * H_ + h) * HD_ + hd)) * S_ + s0 + quad * 4;
      #pragma unroll
      for (int r = 0; r < 4; ++r)
        dst[base + r] = f2bf(accs[j][r] + bv_);
    }
  }
}

// ---------------------------------------------------------------------------
// Kernel 2: flash attention. One wave = 16 q-rows; workgroup = 64 q-rows.
// Q,K: [b,h,s,hd] bf16; Vt: [b,h,hd,s] bf16; ctx out: [b,s,h*hd] bf16
// (staged in the low half of d_out; consumed by out_proj before ln overwrites).
// ---------------------------------------------------------------------------
__global__ __launch_bounds__(256) void attn_kernel(
    const unsigned short* __restrict__ Q, const unsigned short* __restrict__ K,
    const unsigned short* __restrict__ Vt, const int* __restrict__ mask,
    unsigned short* __restrict__ ctx)
{
  __shared__ float lds_p[4][16][32];

  const int wv   = threadIdx.x >> 6;
  const int lane = threadIdx.x & 63;
  const int c    = lane & 15;
  const int quad = lane >> 4;

  const int bh = blockIdx.y;
  const int b  = bh >> 4;
  const int h  = bh & 15;
  const int q0 = blockIdx.x * 64 + wv * 16;

  const unsigned short* Qb = Q  + (size_t)bh * S_ * HD_;
  const unsigned short* Kb = K  + (size_t)bh * S_ * HD_;
  const unsigned short* Vb = Vt + (size_t)bh * HD_ * S_;
  const int* mrow = mask + b * S_;

  short8 aQ0 = *(const short8*)(Qb + (size_t)(q0 + c) * HD_ + quad * 8);
  short8 aQ1 = *(const short8*)(Qb + (size_t)(q0 + c) * HD_ + 32 + quad * 8);

  float m_i[4] = {-1e30f, -1e30f, -1e30f, -1e30f};
  float l_i[4] = {0.f, 0.f, 0.f, 0.f};
  floatx4 acc[4];
  #pragma unroll
  for (int d = 0; d < 4; ++d) acc[d] = (floatx4){0.f, 0.f, 0.f, 0.f};

  for (int t = 0; t < S_ / 32; ++t) {
    const int kp0 = t * 32;
    const float mb0 = (mrow[kp0 + c]      == 0) ? -1e9f : 0.f;
    const float mb1 = (mrow[kp0 + 16 + c] == 0) ? -1e9f : 0.f;

    short8 bK00 = *(const short8*)(Kb + (size_t)(kp0 + c)      * HD_ + quad * 8);
    short8 bK01 = *(const short8*)(Kb + (size_t)(kp0 + c)      * HD_ + 32 + quad * 8);
    short8 bK10 = *(const short8*)(Kb + (size_t)(kp0 + 16 + c) * HD_ + quad * 8);
    short8 bK11 = *(const short8*)(Kb + (size_t)(kp0 + 16 + c) * HD_ + 32 + quad * 8);

    floatx4 C0 = {0.f,0.f,0.f,0.f}, C1 = {0.f,0.f,0.f,0.f};
    C0 = __builtin_amdgcn_mfma_f32_16x16x32_bf16(aQ0, bK00, C0, 0, 0, 0);
    C0 = __builtin_amdgcn_mfma_f32_16x16x32_bf16(aQ1, bK01, C0, 0, 0, 0);
    C1 = __builtin_amdgcn_mfma_f32_16x16x32_bf16(aQ0, bK10, C1, 0, 0, 0);
    C1 = __builtin_amdgcn_mfma_f32_16x16x32_bf16(aQ1, bK11, C1, 0, 0, 0);

    float s0[4], s1[4], tmax[4];
    #pragma unroll
    for (int r = 0; r < 4; ++r) {
      s0[r] = C0[r] * 0.125f + mb0;
      s1[r] = C1[r] * 0.125f + mb1;
      tmax[r] = fmaxf(s0[r], s1[r]);
    }
    #pragma unroll
    for (int off = 1; off < 16; off <<= 1) {
      #pragma unroll
      for (int r = 0; r < 4; ++r)
        tmax[r] = fmaxf(tmax[r], __shfl_xor(tmax[r], off, 16));
    }

    float p0[4], p1[4], rsum[4], alpha[4];
    #pragma unroll
    for (int r = 0; r < 4; ++r) {
      float mnew = fmaxf(m_i[r], tmax[r]);
      alpha[r] = __expf(m_i[r] - mnew);
      p0[r] = __expf(s0[r] - mnew);
      p1[r] = __expf(s1[r] - mnew);
      rsum[r] = p0[r] + p1[r];
      m_i[r] = mnew;
    }
    #pragma unroll
    for (int off = 1; off < 16; off <<= 1) {
      #pragma unroll
      for (int r = 0; r < 4; ++r)
        rsum[r] += __shfl_xor(rsum[r], off, 16);
    }
    #pragma unroll
    for (int r = 0; r < 4; ++r) {
      l_i[r] = l_i[r] * alpha[r] + rsum[r];
      acc[0][r] *= alpha[r];
      acc[1][r] *= alpha[r];
      acc[2][r] *= alpha[r];
      acc[3][r] *= alpha[r];
    }

    #pragma unroll
    for (int r = 0; r < 4; ++r) {
      lds_p[wv][quad * 4 + r][c]      = p0[r];
      lds_p[wv][quad * 4 + r][16 + c] = p1[r];
    }
    __syncthreads();
    const float* pr = &lds_p[wv][c][quad * 8];
    short8 aP;
    #pragma unroll
    for (int j = 0; j < 8; ++j) aP[j] = (short)f2bf(pr[j]);
    __syncthreads();

    #pragma unroll
    for (int d = 0; d < 4; ++d) {
      short8 bV = *(const short8*)(Vb + (size_t)(d * 16 + c) * S_ + kp0 + quad * 8);
      acc[d] = __builtin_amdgcn_mfma_f32_16x16x32_bf16(aP, bV, acc[d], 0, 0, 0);
    }
  }

  float inv[4];
  #pragma unroll
  for (int r = 0; r < 4; ++r) inv[r] = 1.f / l_i[r];
  #pragma unroll
  for (int d = 0; d < 4; ++d) {
    #pragma unroll
    for (int r = 0; r < 4; ++r) {
      int srow = q0 + quad * 4 + r;
      ctx[((size_t)(b * S_ + srow)) * D_ + h * HD_ + d * 16 + c] =
          f2bf(acc[d][r] * inv[r]);
    }
  }
}

// ---------------------------------------------------------------------------
// Kernel 3: out-proj + residual. y[m,n] = ctx@Wo.T + bo + x. y stored FP32.
// ---------------------------------------------------------------------------
__global__ __launch_bounds__(256) void out_proj(
    const unsigned short* __restrict__ CTX, const unsigned short* __restrict__ W,
    const float* __restrict__ bo, const float* __restrict__ X,
    float* __restrict__ Y)
{
  const int wv   = threadIdx.x >> 6;
  const int lane = threadIdx.x & 63;
  const int c    = lane & 15;
  const int quad = lane >> 4;
  const int m0   = blockIdx.x * 64 + wv * 16;
  const int n0   = blockIdx.y * 64;

  const unsigned short* arow = CTX + (size_t)(m0 + c) * D_ + quad * 8;
  const unsigned short* brow = W   + (size_t)(n0 + c) * D_ + quad * 8;

  floatx4 acc0 = {0.f,0.f,0.f,0.f}, acc1 = {0.f,0.f,0.f,0.f};
  floatx4 acc2 = {0.f,0.f,0.f,0.f}, acc3 = {0.f,0.f,0.f,0.f};

  for (int k0 = 0; k0 < D_; k0 += 32) {
    short8 a  = *(const short8*)(arow + k0);
    short8 b0 = *(const short8*)(brow + k0);
    short8 b1 = *(const short8*)(brow + 16 * D_ + k0);
    short8 b2 = *(const short8*)(brow + 32 * D_ + k0);
    short8 b3 = *(const short8*)(brow + 48 * D_ + k0);
    acc0 = __builtin_amdgcn_mfma_f32_16x16x32_bf16(a, b0, acc0, 0, 0, 0);
    acc1 = __builtin_amdgcn_mfma_f32_16x16x32_bf16(a, b1, acc1, 0, 0, 0);
    acc2 = __builtin_amdgcn_mfma_f32_16x16x32_bf16(a, b2, acc2, 0, 0, 0);
    acc3 = __builtin_amdgcn_mfma_f32_16x16x32_bf16(a, b3, acc3, 0, 0, 0);
  }

  floatx4 accs[4] = {acc0, acc1, acc2, acc3};
  #pragma unroll
  for (int j = 0; j < 4; ++j) {
    const int n = n0 + j * 16 + c;
    const float bias = bo[n];
    #pragma unroll
    for (int r = 0; r < 4; ++r) {
      const int m = m0 + quad * 4 + r;
      Y[(size_t)m * D_ + n] = accs[j][r] + bias + X[(size_t)m * D_ + n];
    }
  }
}

// ---------------------------------------------------------------------------
// Kernel 4: LayerNorm over last dim (1024). y fp32 in; OUTPUT FP32.
// ---------------------------------------------------------------------------
__global__ __launch_bounds__(256) void ln_kernel(
    const float* __restrict__ Y, const float* __restrict__ gamma,
    const float* __restrict__ beta, float* __restrict__ out)
{
  __shared__ float red[2][4];
  const int row  = blockIdx.x;
  const int tid  = threadIdx.x;
  const int wv   = tid >> 6;
  const int lane = tid & 63;
  const float* y = Y + (size_t)row * D_;

  float v[4];
  float sum = 0.f, sumsq = 0.f;
  #pragma unroll
  for (int i = 0; i < 4; ++i) {
    v[i] = y[tid + i * 256];
    sum += v[i];
    sumsq += v[i] * v[i];
  }
  #pragma unroll
  for (int off = 32; off > 0; off >>= 1) {
    sum   += __shfl_down(sum, off, 64);
    sumsq += __shfl_down(sumsq, off, 64);
  }
  if (lane == 0) { red[0][wv] = sum; red[1][wv] = sumsq; }
  __syncthreads();
  sum   = red[0][0] + red[0][1] + red[0][2] + red[0][3];
  sumsq = red[1][0] + red[1][1] + red[1][2] + red[1][3];

  const float mu   = sum * (1.f / D_);
  const float var  = sumsq * (1.f / D_) - mu * mu;
  const float rstd = rsqrtf(var + 1e-5f);

  #pragma unroll
  for (int i = 0; i < 4; ++i) {
    const int col = tid + i * 256;
    out[(size_t)row * D_ + col] = (v[i] - mu) * rstd * gamma[col] + beta[col];
  }
}

// ---------------------------------------------------------------------------
extern "C" void kernel_launch(void* const* d_in, const int* in_sizes, int n_in,
                              void* d_out, int out_size, void* d_ws, size_t ws_size,
                              hipStream_t stream) {
  const float* x     = (const float*)d_in[0];
  const int*   mask  = (const int*)d_in[1];
  const float* Wq    = (const float*)d_in[2];
  const float* bq    = (const float*)d_in[3];
  const float* Wk    = (const float*)d_in[4];
  const float* bk    = (const float*)d_in[5];
  const float* Wv    = (const float*)d_in[6];
  const float* bv    = (const float*)d_in[7];
  const float* Wo    = (const float*)d_in[8];
  const float* bo    = (const float*)d_in[9];
  const float* gamma = (const float*)d_in[10];
  const float* beta  = (const float*)d_in[11];

  char* ws = (char*)d_ws;
  unsigned short* xb    = (unsigned short*)(ws + WS_XB);
  unsigned short* wqb   = (unsigned short*)(ws + WS_WQ);
  unsigned short* wkb   = (unsigned short*)(ws + WS_WK);
  unsigned short* wvb   = (unsigned short*)(ws + WS_WV);
  unsigned short* wob   = (unsigned short*)(ws + WS_WO);
  unsigned short* q_ws  = (unsigned short*)(ws + WS_Q);
  unsigned short* k_ws  = (unsigned short*)(ws + WS_KK);
  unsigned short* vt_ws = (unsigned short*)(ws + WS_VT);
  float*          y_ws  = (float*)(ws + WS_Y);   // overlays Q+K (dead by then)
  unsigned short* ctx   = (unsigned short*)d_out; // low 16MB of 32MB fp32 buf

  const int nx4 = (BS_ * D_) / 4;
  const int nw4 = (D_ * D_) / 4;
  cvt_f32_bf16<<<(nx4 + 255) / 256, 256, 0, stream>>>(x,  xb,  nx4);
  cvt_f32_bf16<<<(nw4 + 255) / 256, 256, 0, stream>>>(Wq, wqb, nw4);
  cvt_f32_bf16<<<(nw4 + 255) / 256, 256, 0, stream>>>(Wk, wkb, nw4);
  cvt_f32_bf16<<<(nw4 + 255) / 256, 256, 0, stream>>>(Wv, wvb, nw4);
  cvt_f32_bf16<<<(nw4 + 255) / 256, 256, 0, stream>>>(Wo, wob, nw4);

  proj_qkv<<<dim3(BS_ / 64, D_ / 64, 3), 256, 0, stream>>>(
      xb, wqb, bq, wkb, bk, wvb, bv, q_ws, k_ws, vt_ws);

  attn_kernel<<<dim3(S_ / 64, B_ * H_), 256, 0, stream>>>(
      q_ws, k_ws, vt_ws, mask, ctx);

  out_proj<<<dim3(BS_ / 64, D_ / 64), 256, 0, stream>>>(
      ctx, wob, bo, x, y_ws);

  ln_kernel<<<BS_, 256, 0, stream>>>(y_ws, gamma, beta, (float*)d_out);
}